// Round 1
// baseline (2564.943 us; speedup 1.0000x reference)
//
#include <hip/hip_runtime.h>

#define N_E   4096
#define E_DIM 256
#define NTOK  32768
#define ZX    4096      // h*w*d = 16*16*16
#define DECAY 0.99f
#define EPSV  1e-5f
#define TAU   0.0625f
#define SJ    4         // j-splits
#define BT    128       // token tile
#define BJ    128       // code tile
#define BK    16        // k chunk
#define LDST  132       // padded LDS row stride (floats)

// ---------------- init: zero accumulators ----------------
__global__ void k_init(float* __restrict__ dw, float* __restrict__ n_total,
                       int* __restrict__ flagCount) {
    int gid = blockIdx.x * blockDim.x + threadIdx.x;
    int stride = gridDim.x * blockDim.x;
    for (int i = gid; i < N_E * E_DIM; i += stride) dw[i] = 0.f;
    if (gid < N_E) n_total[gid] = 0.f;
    if (gid == 0) *flagCount = 0;
}

// ---------------- permute z (b,c,x) -> zfT[c][b*4096+x] ----------------
__global__ void k_permute(const float* __restrict__ z, float* __restrict__ zfT) {
    int gid = blockIdx.x * blockDim.x + threadIdx.x;   // over float4 of output, 2,097,152 total
    const float4* z4 = (const float4*)z;
    float4* o4 = (float4*)zfT;
    int x4 = gid & 1023;          // ZX/4
    int b  = (gid >> 10) & 7;
    int c  = gid >> 13;
    o4[gid] = z4[(b * E_DIM + c) * 1024 + x4];
}

// ---------------- ||e_j||^2 ----------------
__global__ void k_enorm(const float* __restrict__ emb, float* __restrict__ enorm) {
    int j = blockIdx.x * 4 + (threadIdx.x >> 6);
    int lane = threadIdx.x & 63;
    float4 v = ((const float4*)emb)[j * 64 + lane];
    float s = v.x * v.x + v.y * v.y + v.z * v.z + v.w * v.w;
    #pragma unroll
    for (int off = 32; off; off >>= 1) s += __shfl_down(s, off, 64);
    if (lane == 0) enorm[j] = s;
}

// ---------------- main distance / top-2 argmin ----------------
__global__ __launch_bounds__(256, 4) void k_dist(
        const float* __restrict__ zfT, const float* __restrict__ emb,
        const float* __restrict__ enorm,
        float* __restrict__ pm1, float* __restrict__ pm2, int* __restrict__ pidx) {
    __shared__ float sza[BK * LDST];
    __shared__ float seb[BK * LDST];
    __shared__ float ens[BJ];
    const int tid = threadIdx.x;
    const int tx = tid & 15, ty = tid >> 4;
    const int t0 = blockIdx.x * BT;
    const int j0 = blockIdx.y * (N_E / SJ);

    float m1[8], m2[8]; int x1[8];
    #pragma unroll
    for (int i = 0; i < 8; i++) { m1[i] = 3.4e38f; m2[i] = 3.4e38f; x1[i] = 0; }

    for (int jt = 0; jt < N_E / SJ; jt += BJ) {
        const int jbase = j0 + jt;
        __syncthreads();                       // prior epilogue done with ens, compute done with sza/seb
        if (tid < BJ) ens[tid] = enorm[jbase + tid];

        float acc[8][8];
        #pragma unroll
        for (int i = 0; i < 8; i++)
            #pragma unroll
            for (int jj = 0; jj < 8; jj++) acc[i][jj] = 0.f;

        for (int k0 = 0; k0 < E_DIM; k0 += BK) {
            // stage za[k][t]: 16 x 128 from zfT
            #pragma unroll
            for (int r = 0; r < 2; r++) {
                int q = tid + 256 * r;
                int k = q >> 5, t4 = q & 31;
                float4 v = ((const float4*)zfT)[(size_t)(k0 + k) * (NTOK / 4) + (t0 >> 2) + t4];
                *(float4*)&sza[k * LDST + t4 * 4] = v;
            }
            // stage eb[k][j]: transpose 128 x 16 from emb
            #pragma unroll
            for (int r = 0; r < 2; r++) {
                int q = tid + 256 * r;
                int kq = q & 3, j = q >> 2;
                float4 v = ((const float4*)emb)[(size_t)(jbase + j) * (E_DIM / 4) + (k0 >> 2) + kq];
                seb[(kq * 4 + 0) * LDST + j] = v.x;
                seb[(kq * 4 + 1) * LDST + j] = v.y;
                seb[(kq * 4 + 2) * LDST + j] = v.z;
                seb[(kq * 4 + 3) * LDST + j] = v.w;
            }
            __syncthreads();
            #pragma unroll
            for (int k = 0; k < BK; k++) {
                float4 a0 = *(const float4*)&sza[k * LDST + ty * 8];
                float4 a1 = *(const float4*)&sza[k * LDST + ty * 8 + 4];
                float4 b0 = *(const float4*)&seb[k * LDST + tx * 8];
                float4 b1 = *(const float4*)&seb[k * LDST + tx * 8 + 4];
                float a[8] = {a0.x, a0.y, a0.z, a0.w, a1.x, a1.y, a1.z, a1.w};
                float b[8] = {b0.x, b0.y, b0.z, b0.w, b1.x, b1.y, b1.z, b1.w};
                #pragma unroll
                for (int i = 0; i < 8; i++)
                    #pragma unroll
                    for (int jj = 0; jj < 8; jj++)
                        acc[i][jj] = fmaf(a[i], b[jj], acc[i][jj]);
            }
            __syncthreads();
        }
        // epilogue: score = ||e||^2 - 2 z.e  (||z||^2 constant per token, argmin-invariant)
        #pragma unroll
        for (int jj = 0; jj < 8; jj++) {
            const int j = jbase + tx * 8 + jj;
            const float en = ens[tx * 8 + jj];
            #pragma unroll
            for (int i = 0; i < 8; i++) {
                float s = fmaf(-2.f, acc[i][jj], en);
                if (s < m1[i]) { m2[i] = m1[i]; m1[i] = s; x1[i] = j; }
                else if (s < m2[i]) { m2[i] = s; }
            }
        }
    }
    // merge top-2 across the 16 lanes sharing each token row (tie -> lower index)
    #pragma unroll
    for (int off = 1; off < 16; off <<= 1) {
        #pragma unroll
        for (int i = 0; i < 8; i++) {
            float om1 = __shfl_xor(m1[i], off, 16);
            float om2 = __shfl_xor(m2[i], off, 16);
            int   ox1 = __shfl_xor(x1[i], off, 16);
            bool take = (om1 < m1[i]) || (om1 == m1[i] && ox1 < x1[i]);
            float n2 = take ? fminf(m1[i], om2) : fminf(om1, m2[i]);
            if (take) { m1[i] = om1; x1[i] = ox1; }
            m2[i] = n2;
        }
    }
    if (tx == 0) {
        #pragma unroll
        for (int i = 0; i < 8; i++) {
            int t = t0 + ty * 8 + i;
            pm1[(size_t)t * SJ + blockIdx.y] = m1[i];
            pm2[(size_t)t * SJ + blockIdx.y] = m2[i];
            pidx[(size_t)t * SJ + blockIdx.y] = x1[i];
        }
    }
}

// ---------------- merge j-splits, flag near-ties ----------------
__global__ void k_merge(const float* __restrict__ pm1, const float* __restrict__ pm2,
                        const int* __restrict__ pidx, int* __restrict__ idx32,
                        int* __restrict__ flagList, int* __restrict__ flagCount) {
    int t = blockIdx.x * blockDim.x + threadIdx.x;
    if (t >= NTOK) return;
    float m1 = 3.4e38f, m2 = 3.4e38f; int x1 = 0x7fffffff;
    for (int s = 0; s < SJ; s++) {
        float om1 = pm1[(size_t)t * SJ + s], om2 = pm2[(size_t)t * SJ + s];
        int ox1 = pidx[(size_t)t * SJ + s];
        bool take = (om1 < m1) || (om1 == m1 && ox1 < x1);
        float n2 = take ? fminf(m1, om2) : fminf(om1, m2);
        if (take) { m1 = om1; x1 = ox1; }
        m2 = n2;
    }
    idx32[t] = x1;
    if (m2 - m1 < TAU) {
        int p = atomicAdd(flagCount, 1);
        flagList[p] = t;
    }
}

// ---------------- fp64 recheck of near-tie tokens (full row) ----------------
__global__ void k_recheck(const float* __restrict__ zfT, const float* __restrict__ emb,
                          const int* __restrict__ flagList, const int* __restrict__ flagCount,
                          int* __restrict__ idx32) {
    __shared__ float zrow[E_DIM];
    __shared__ double rv[256];
    __shared__ int ri[256];
    const int tid = threadIdx.x;
    const int nf = *flagCount;
    for (int f = blockIdx.x; f < nf; f += gridDim.x) {
        const int t = flagList[f];
        __syncthreads();
        zrow[tid] = zfT[(size_t)tid * NTOK + t];
        __syncthreads();
        double best = 1e300; int bi = 0x7fffffff;
        for (int s = 0; s < N_E / 256; s++) {
            int j = s * 256 + tid;
            const float* er = emb + (size_t)j * E_DIM;
            double a1 = 0.0, a2 = 0.0;
            for (int k = 0; k < E_DIM; k++) {
                double e = (double)er[k];
                a1 = fma(e, (double)zrow[k], a1);
                a2 = fma(e, e, a2);
            }
            double d = a2 - 2.0 * a1;   // ||z||^2 constant omitted
            if (d < best || (d == best && j < bi)) { best = d; bi = j; }
        }
        rv[tid] = best; ri[tid] = bi;
        __syncthreads();
        for (int off = 128; off; off >>= 1) {
            if (tid < off) {
                if (rv[tid + off] < rv[tid] ||
                    (rv[tid + off] == rv[tid] && ri[tid + off] < ri[tid])) {
                    rv[tid] = rv[tid + off]; ri[tid] = ri[tid + off];
                }
            }
            __syncthreads();
        }
        if (tid == 0) idx32[t] = ri[0];
        __syncthreads();
    }
}

// ---------------- histogram + idx output ----------------
__global__ void k_count(const int* __restrict__ idx32, float* __restrict__ n_total,
                        float* __restrict__ out_idx) {
    int t = blockIdx.x * blockDim.x + threadIdx.x;
    if (t >= NTOK) return;
    int j = idx32[t];
    atomicAdd(&n_total[j], 1.0f);
    out_idx[t] = (float)j;
}

// ---------------- dw scatter-add ----------------
__global__ void k_scatter(const float* __restrict__ zfT, const int* __restrict__ idx32,
                          float* __restrict__ dw) {
    int t = blockIdx.x * blockDim.x + threadIdx.x;
    int k4 = blockIdx.y;
    int j = idx32[t];
    #pragma unroll
    for (int u = 0; u < 4; u++) {
        float v = zfT[(size_t)(k4 * 4 + u) * NTOK + t];
        atomicAdd(&dw[(size_t)j * E_DIM + k4 * 4 + u], v);
    }
}

// ---------------- zq gather (writes in z layout) ----------------
__global__ void k_zq(const float* __restrict__ emb, const int* __restrict__ idx32,
                     float* __restrict__ out_zq) {
    int t = blockIdx.x * blockDim.x + threadIdx.x;
    int j = idx32[t];
    int b = t >> 12, x = t & 4095;
    const float4* er = (const float4*)(emb + (size_t)j * E_DIM);
    float* ob = out_zq + (size_t)b * (E_DIM * ZX) + x;
    #pragma unroll 8
    for (int c4 = 0; c4 < E_DIM / 4; c4++) {
        float4 v = er[c4];
        ob[(size_t)(c4 * 4 + 0) * ZX] = v.x;
        ob[(size_t)(c4 * 4 + 1) * ZX] = v.y;
        ob[(size_t)(c4 * 4 + 2) * ZX] = v.z;
        ob[(size_t)(c4 * 4 + 3) * ZX] = v.w;
    }
}

// ---------------- n = sum(new_cluster), usage ----------------
__global__ void k_stats(const float* __restrict__ cluster_size, const float* __restrict__ n_total,
                        float* __restrict__ nval, float* __restrict__ out_usage) {
    __shared__ float sn[256];
    __shared__ float sc[256];
    int tid = threadIdx.x;
    float ns = 0.f, cnt = 0.f;
    for (int j = tid; j < N_E; j += 256) {
        float nc = cluster_size[j] * DECAY + (1.f - DECAY) * n_total[j];
        ns += nc;
        cnt += (n_total[j] > 0.f) ? 1.f : 0.f;
    }
    sn[tid] = ns; sc[tid] = cnt;
    __syncthreads();
    for (int off = 128; off; off >>= 1) {
        if (tid < off) { sn[tid] += sn[tid + off]; sc[tid] += sc[tid + off]; }
        __syncthreads();
    }
    if (tid == 0) { *nval = sn[0]; *out_usage = sc[0] / (float)N_E; }
}

// ---------------- EMA epilogue ----------------
__global__ void k_final(const float* __restrict__ cluster_size, const float* __restrict__ n_total,
                        const float* __restrict__ emb_avg, const float* __restrict__ dw,
                        const float* __restrict__ nval,
                        float* __restrict__ out_cluster, float* __restrict__ out_avg,
                        float* __restrict__ out_embed) {
    int j = blockIdx.x;
    int k = threadIdx.x;
    float nc = cluster_size[j] * DECAY + (1.f - DECAY) * n_total[j];
    float n = *nval;
    float cs = (nc + EPSV) / (n + (float)N_E * EPSV) * n;
    float na = emb_avg[(size_t)j * E_DIM + k] * DECAY + (1.f - DECAY) * dw[(size_t)j * E_DIM + k];
    out_avg[(size_t)j * E_DIM + k] = na;
    out_embed[(size_t)j * E_DIM + k] = na / cs;
    if (k == 0) out_cluster[j] = nc;
}

extern "C" void kernel_launch(void* const* d_in, const int* in_sizes, int n_in,
                              void* d_out, int out_size, void* d_ws, size_t ws_size,
                              hipStream_t stream) {
    const float* z            = (const float*)d_in[0];
    const float* emb          = (const float*)d_in[1];
    const float* cluster_size = (const float*)d_in[2];
    const float* emb_avg      = (const float*)d_in[3];
    float* out = (float*)d_out;

    // workspace layout (bytes)
    char* ws = (char*)d_ws;
    float* zfT      = (float*)(ws + 0);           // 33,554,432 B
    float* dw       = (float*)(ws + 33554432);    //  4,194,304 B
    float* n_total  = (float*)(ws + 37748736);    //     16,384 B
    float* enorm    = (float*)(ws + 37765120);    //     16,384 B
    float* pm1      = (float*)(ws + 37781504);    //    524,288 B
    float* pm2      = (float*)(ws + 38305792);    //    524,288 B
    int*   pidx     = (int*)  (ws + 38830080);    //    524,288 B
    int*   idx32    = (int*)  (ws + 39354368);    //    131,072 B
    int*   flagList = (int*)  (ws + 39485440);    //    131,072 B
    int*   flagCnt  = (int*)  (ws + 39616512);    //         64 B
    float* nval     = (float*)(ws + 39616576);    //         64 B

    // output sections
    float* out_zq      = out + 0;
    float* out_idx     = out + 8388608;
    float* out_cluster = out + 8421376;
    float* out_avg     = out + 8425472;
    float* out_embed   = out + 9474048;
    float* out_usage   = out + 10522624;

    hipLaunchKernelGGL(k_init,     dim3(1024), dim3(256), 0, stream, dw, n_total, flagCnt);
    hipLaunchKernelGGL(k_permute,  dim3(8192), dim3(256), 0, stream, z, zfT);
    hipLaunchKernelGGL(k_enorm,    dim3(1024), dim3(256), 0, stream, emb, enorm);
    hipLaunchKernelGGL(k_dist,     dim3(256, SJ), dim3(256), 0, stream,
                       zfT, emb, enorm, pm1, pm2, pidx);
    hipLaunchKernelGGL(k_merge,    dim3(128), dim3(256), 0, stream,
                       pm1, pm2, pidx, idx32, flagList, flagCnt);
    hipLaunchKernelGGL(k_recheck,  dim3(256), dim3(256), 0, stream,
                       zfT, emb, flagList, flagCnt, idx32);
    hipLaunchKernelGGL(k_count,    dim3(128), dim3(256), 0, stream, idx32, n_total, out_idx);
    hipLaunchKernelGGL(k_scatter,  dim3(128, 64), dim3(256), 0, stream, zfT, idx32, dw);
    hipLaunchKernelGGL(k_zq,       dim3(128), dim3(256), 0, stream, emb, idx32, out_zq);
    hipLaunchKernelGGL(k_stats,    dim3(1), dim3(256), 0, stream,
                       cluster_size, n_total, nval, out_usage);
    hipLaunchKernelGGL(k_final,    dim3(4096), dim3(256), 0, stream,
                       cluster_size, n_total, emb_avg, dw, nval,
                       out_cluster, out_avg, out_embed);
}

// Round 2
// 894.101 us; speedup vs baseline: 2.8687x; 2.8687x over previous
//
#include <hip/hip_runtime.h>

#define N_E   4096
#define E_DIM 256
#define NTOK  32768
#define ZX    4096
#define DECAY 0.99f
#define EPSV  1e-5f
#define TAU   0.05f
#define NJB   32        // N_E / 128 j-blocks
#define KP    768       // split-GEMM K

typedef __attribute__((ext_vector_type(8))) short short8;
typedef __attribute__((ext_vector_type(4))) float f32x4;

__device__ __forceinline__ unsigned short f2bf(float x) {
    unsigned u = __float_as_uint(x);
    unsigned r = (u + 0x7fff + ((u >> 16) & 1)) >> 16;
    return (unsigned short)r;
}
__device__ __forceinline__ float bf2f(unsigned short h) {
    return __uint_as_float(((unsigned)h) << 16);
}
__device__ __forceinline__ void gload16(const void* g, void* l) {
    __builtin_amdgcn_global_load_lds(
        (const __attribute__((address_space(1))) char*)g,
        (__attribute__((address_space(3))) char*)l, 16, 0, 0);
}

// ---------------- prep z: (b,c,x) fp32 -> zh/zl [t][c] bf16 ----------------
__global__ void k_prep_z(const float* __restrict__ z,
                         unsigned short* __restrict__ zh, unsigned short* __restrict__ zl) {
    __shared__ float lt[64][65];
    const int bid = blockIdx.x;
    const int xt = bid & 63, ct = (bid >> 6) & 3, b = bid >> 8;
    const int tid = threadIdx.x;
    #pragma unroll
    for (int r = 0; r < 4; ++r) {
        int cy = r * 16 + (tid >> 4);
        int xx4 = tid & 15;
        float4 v = ((const float4*)z)[(size_t)(b * 256 + ct * 64 + cy) * 1024 + xt * 16 + xx4];
        lt[cy][xx4 * 4 + 0] = v.x; lt[cy][xx4 * 4 + 1] = v.y;
        lt[cy][xx4 * 4 + 2] = v.z; lt[cy][xx4 * 4 + 3] = v.w;
    }
    __syncthreads();
    #pragma unroll
    for (int it = 0; it < 2; ++it) {
        int tl = it * 32 + (tid >> 3);
        int c8 = tid & 7;
        unsigned short h[8], l[8];
        #pragma unroll
        for (int u = 0; u < 8; ++u) {
            float f = lt[c8 * 8 + u][tl];
            h[u] = f2bf(f);
            l[u] = f2bf(f - bf2f(h[u]));
        }
        size_t t = (size_t)(b * 4096 + xt * 64 + tl);
        size_t o = t * 256 + ct * 64 + c8 * 8;
        *(ushort4*)&zh[o]     = make_ushort4(h[0], h[1], h[2], h[3]);
        *(ushort4*)&zh[o + 4] = make_ushort4(h[4], h[5], h[6], h[7]);
        *(ushort4*)&zl[o]     = make_ushort4(l[0], l[1], l[2], l[3]);
        *(ushort4*)&zl[o + 4] = make_ushort4(l[4], l[5], l[6], l[7]);
    }
}

// ---------------- prep emb: B' = [e_hi | e_lo | e_hi], enorm32/64 ----------------
__global__ void k_prep_e(const float* __restrict__ emb, unsigned short* __restrict__ Bp,
                         float* __restrict__ enorm32, double* __restrict__ enorm64) {
    int j = blockIdx.x * 4 + (threadIdx.x >> 6);
    int lane = threadIdx.x & 63;
    float4 v = ((const float4*)emb)[(size_t)j * 64 + lane];
    float f[4] = {v.x, v.y, v.z, v.w};
    unsigned short h[4], l[4];
    #pragma unroll
    for (int u = 0; u < 4; ++u) {
        h[u] = f2bf(f[u]);
        l[u] = f2bf(f[u] - bf2f(h[u]));
    }
    size_t base = (size_t)j * KP;
    *(ushort4*)&Bp[base + lane * 4]       = make_ushort4(h[0], h[1], h[2], h[3]);
    *(ushort4*)&Bp[base + 256 + lane * 4] = make_ushort4(l[0], l[1], l[2], l[3]);
    *(ushort4*)&Bp[base + 512 + lane * 4] = make_ushort4(h[0], h[1], h[2], h[3]);
    double s = 0.0;
    #pragma unroll
    for (int u = 0; u < 4; ++u) s += (double)f[u] * (double)f[u];
    #pragma unroll
    for (int off = 32; off; off >>= 1) s += __shfl_down(s, off, 64);
    if (lane == 0) { enorm32[j] = (float)s; enorm64[j] = s; }
}

// ---------------- init ----------------
__global__ void k_init(int* __restrict__ cnt, int* __restrict__ flagCount) {
    int gid = blockIdx.x * blockDim.x + threadIdx.x;
    if (gid < N_E) cnt[gid] = 0;
    if (gid == 0) *flagCount = 0;
}

// ---------------- MFMA distance / top-2 argmin ----------------
__global__ __launch_bounds__(256) void k_dist(
        const unsigned short* __restrict__ zh, const unsigned short* __restrict__ zl,
        const unsigned short* __restrict__ Bp, const float* __restrict__ enorm32,
        float* __restrict__ pm1, float* __restrict__ pm2, int* __restrict__ pidx) {
    __shared__ __align__(16) char smem[32768];
    const int tid = threadIdx.x;
    const int lane = tid & 63;
    const int w = tid >> 6;
    const int wr = w >> 1, wc = w & 1;
    const int t0 = blockIdx.x * 128;
    const int jb = blockIdx.y;
    const int j0 = jb * 128;

    f32x4 acc[4][4];
    #pragma unroll
    for (int m = 0; m < 4; ++m)
        #pragma unroll
        for (int n = 0; n < 4; ++n)
            acc[m][n] = (f32x4){0.f, 0.f, 0.f, 0.f};

    for (int s = 0; s < 12; ++s) {
        const unsigned short* As = (s < 8) ? zh : zl;
        const int akb = (s & 3) * 128 + ((lane & 7) << 4);   // byte offset in 512B row
        const int bkb = s * 128 + ((lane & 7) << 4);         // byte offset in 1536B row
        #pragma unroll
        for (int c = 0; c < 4; ++c) {
            int seg = w * 4 + c;
            int arow = t0 + seg * 8 + (lane >> 3);
            int brow = j0 + seg * 8 + (lane >> 3);
            gload16((const char*)As + (size_t)arow * 512 + akb, &smem[seg * 1024]);
            gload16((const char*)Bp + (size_t)brow * 1536 + bkb, &smem[16384 + seg * 1024]);
        }
        __syncthreads();
        #pragma unroll
        for (int kk = 0; kk < 2; ++kk) {
            short8 a[4], b[4];
            #pragma unroll
            for (int m = 0; m < 4; ++m)
                a[m] = *(const short8*)&smem[((wr * 64 + m * 16 + (lane & 15)) << 7)
                                             + kk * 64 + ((lane >> 4) << 4)];
            #pragma unroll
            for (int n = 0; n < 4; ++n)
                b[n] = *(const short8*)&smem[16384 + ((wc * 64 + n * 16 + (lane & 15)) << 7)
                                             + kk * 64 + ((lane >> 4) << 4)];
            #pragma unroll
            for (int m = 0; m < 4; ++m)
                #pragma unroll
                for (int n = 0; n < 4; ++n)
                    acc[m][n] = __builtin_amdgcn_mfma_f32_16x16x32_bf16(a[m], b[n], acc[m][n], 0, 0, 0);
        }
        __syncthreads();
    }

    // epilogue: score = ||e||^2 - 2 z.e ; per-token top-2 over this block's 128 codes
    float bm1[4][4], bm2[4][4]; int bx1[4][4];
    #pragma unroll
    for (int m = 0; m < 4; ++m)
        #pragma unroll
        for (int r = 0; r < 4; ++r) { bm1[m][r] = 3.4e38f; bm2[m][r] = 3.4e38f; bx1[m][r] = 0; }
    #pragma unroll
    for (int n = 0; n < 4; ++n) {
        int j = j0 + wc * 64 + n * 16 + (lane & 15);
        float en = enorm32[j];
        #pragma unroll
        for (int m = 0; m < 4; ++m)
            #pragma unroll
            for (int r = 0; r < 4; ++r) {
                float sc = fmaf(-2.f, acc[m][n][r], en);
                if (sc < bm1[m][r]) { bm2[m][r] = bm1[m][r]; bm1[m][r] = sc; bx1[m][r] = j; }
                else if (sc < bm2[m][r]) bm2[m][r] = sc;
            }
    }
    #pragma unroll
    for (int off = 8; off >= 1; off >>= 1) {
        #pragma unroll
        for (int m = 0; m < 4; ++m)
            #pragma unroll
            for (int r = 0; r < 4; ++r) {
                float om1 = __shfl_xor(bm1[m][r], off, 64);
                float om2 = __shfl_xor(bm2[m][r], off, 64);
                int   ox1 = __shfl_xor(bx1[m][r], off, 64);
                bool take = (om1 < bm1[m][r]) || (om1 == bm1[m][r] && ox1 < bx1[m][r]);
                float n2 = take ? fminf(bm1[m][r], om2) : fminf(om1, bm2[m][r]);
                if (take) { bm1[m][r] = om1; bx1[m][r] = ox1; }
                bm2[m][r] = n2;
            }
    }
    // merge the two wc-waves via LDS (tiles are dead after last barrier)
    float* mb1 = (float*)smem;            // [2][128]
    float* mb2 = (float*)(smem + 1024);
    int*   mbi = (int*)(smem + 2048);
    if ((lane & 15) == 0) {
        int g = lane >> 4;
        #pragma unroll
        for (int m = 0; m < 4; ++m)
            #pragma unroll
            for (int r = 0; r < 4; ++r) {
                int tl = wr * 64 + m * 16 + g * 4 + r;
                mb1[wc * 128 + tl] = bm1[m][r];
                mb2[wc * 128 + tl] = bm2[m][r];
                mbi[wc * 128 + tl] = bx1[m][r];
            }
    }
    __syncthreads();
    if (tid < 128) {
        float a1 = mb1[tid], a2 = mb2[tid]; int ai = mbi[tid];
        float c1 = mb1[128 + tid], c2 = mb2[128 + tid]; int ci = mbi[128 + tid];
        bool take = (c1 < a1) || (c1 == a1 && ci < ai);
        float m1 = take ? c1 : a1;
        int   x1 = take ? ci : ai;
        float m2 = take ? fminf(a1, c2) : fminf(c1, a2);
        int t = t0 + tid;
        pm1[(size_t)jb * NTOK + t] = m1;
        pm2[(size_t)jb * NTOK + t] = m2;
        pidx[(size_t)jb * NTOK + t] = x1;
    }
}

// ---------------- merge j-blocks, flag near-ties ----------------
__global__ void k_merge(const float* __restrict__ pm1, const float* __restrict__ pm2,
                        const int* __restrict__ pidx, int* __restrict__ idx32,
                        int* __restrict__ flagList, int* __restrict__ flagCount) {
    int t = blockIdx.x * blockDim.x + threadIdx.x;
    if (t >= NTOK) return;
    float m1 = 3.4e38f, m2 = 3.4e38f; int x1 = 0x7fffffff;
    for (int s = 0; s < NJB; s++) {
        float om1 = pm1[(size_t)s * NTOK + t], om2 = pm2[(size_t)s * NTOK + t];
        int ox1 = pidx[(size_t)s * NTOK + t];
        bool take = (om1 < m1) || (om1 == m1 && ox1 < x1);
        float n2 = take ? fminf(m1, om2) : fminf(om1, m2);
        if (take) { m1 = om1; x1 = ox1; }
        m2 = n2;
    }
    idx32[t] = x1;
    if (m2 - m1 < TAU) {
        int p = atomicAdd(flagCount, 1);
        flagList[p] = t;
    }
}

// ---------------- fp64 recheck of flagged tokens ----------------
__global__ void k_recheck(const float* __restrict__ z, const float* __restrict__ emb,
                          const double* __restrict__ enorm64,
                          const int* __restrict__ flagList, const int* __restrict__ flagCount,
                          int* __restrict__ idx32) {
    __shared__ float zrow[E_DIM];
    __shared__ double rv[256];
    __shared__ int ri[256];
    const int tid = threadIdx.x;
    const int nf = *flagCount;
    for (int f = blockIdx.x; f < nf; f += gridDim.x) {
        const int t = flagList[f];
        const int b = t >> 12, x = t & 4095;
        __syncthreads();
        zrow[tid] = z[(size_t)(b * 256 + tid) * 4096 + x];
        __syncthreads();
        double best = 1e300; int bi = 0x7fffffff;
        for (int s = 0; s < N_E / 256; s++) {
            int j = s * 256 + tid;
            const float* er = emb + (size_t)j * E_DIM;
            double a1 = 0.0;
            for (int k = 0; k < E_DIM; k++)
                a1 = fma((double)er[k], (double)zrow[k], a1);
            double d = enorm64[j] - 2.0 * a1;
            if (d < best || (d == best && j < bi)) { best = d; bi = j; }
        }
        rv[tid] = best; ri[tid] = bi;
        __syncthreads();
        for (int off = 128; off; off >>= 1) {
            if (tid < off) {
                if (rv[tid + off] < rv[tid] ||
                    (rv[tid + off] == rv[tid] && ri[tid + off] < ri[tid])) {
                    rv[tid] = rv[tid + off]; ri[tid] = ri[tid + off];
                }
            }
            __syncthreads();
        }
        if (tid == 0) idx32[t] = ri[0];
        __syncthreads();
    }
}

// ---------------- histogram + idx output ----------------
__global__ void k_count(const int* __restrict__ idx32, int* __restrict__ cnt,
                        float* __restrict__ out_idx) {
    int t = blockIdx.x * blockDim.x + threadIdx.x;
    if (t >= NTOK) return;
    int j = idx32[t];
    atomicAdd(&cnt[j], 1);
    out_idx[t] = (float)j;
}

// ---------------- exclusive scan of cnt[4096] ----------------
__global__ void k_scan(const int* __restrict__ cnt, int* __restrict__ offs) {
    __shared__ int sc[1024];
    int tid = threadIdx.x;
    int c0 = cnt[tid * 4], c1 = cnt[tid * 4 + 1], c2 = cnt[tid * 4 + 2], c3 = cnt[tid * 4 + 3];
    int ls = c0 + c1 + c2 + c3;
    sc[tid] = ls;
    __syncthreads();
    for (int off = 1; off < 1024; off <<= 1) {
        int v = (tid >= off) ? sc[tid - off] : 0;
        __syncthreads();
        sc[tid] += v;
        __syncthreads();
    }
    int base = sc[tid] - ls;
    offs[tid * 4] = base;
    offs[tid * 4 + 1] = base + c0;
    offs[tid * 4 + 2] = base + c0 + c1;
    offs[tid * 4 + 3] = base + c0 + c1 + c2;
}

// ---------------- place tokens into per-code lists ----------------
__global__ void k_place(const int* __restrict__ idx32, int* __restrict__ offs,
                        int* __restrict__ tokList) {
    int t = blockIdx.x * blockDim.x + threadIdx.x;
    if (t >= NTOK) return;
    int j = idx32[t];
    int p = atomicAdd(&offs[j], 1);
    tokList[p] = t;
}

// ---------------- dw: per-code coalesced reduction (no atomics) ----------------
__global__ void k_dw(const unsigned short* __restrict__ zh, const unsigned short* __restrict__ zl,
                     const int* __restrict__ cnt, const int* __restrict__ offs,
                     const int* __restrict__ tokList, float* __restrict__ dw) {
    int j = blockIdx.x;
    int lane = threadIdx.x;   // 64
    int n = cnt[j];
    int s0 = offs[j] - n;     // offs holds end positions after k_place
    float4 acc = make_float4(0.f, 0.f, 0.f, 0.f);
    for (int i = 0; i < n; ++i) {
        int t = tokList[s0 + i];
        ushort4 h = *(const ushort4*)&zh[(size_t)t * 256 + lane * 4];
        ushort4 l = *(const ushort4*)&zl[(size_t)t * 256 + lane * 4];
        acc.x += bf2f(h.x) + bf2f(l.x);
        acc.y += bf2f(h.y) + bf2f(l.y);
        acc.z += bf2f(h.z) + bf2f(l.z);
        acc.w += bf2f(h.w) + bf2f(l.w);
    }
    *(float4*)&dw[(size_t)j * 256 + lane * 4] = acc;
}

// ---------------- zq gather ----------------
__global__ void k_zq(const float* __restrict__ emb, const int* __restrict__ idx32,
                     float* __restrict__ out_zq) {
    int t = blockIdx.x * blockDim.x + threadIdx.x;
    int j = idx32[t];
    int b = t >> 12, x = t & 4095;
    const float4* er = (const float4*)(emb + (size_t)j * E_DIM);
    float* ob = out_zq + (size_t)b * (E_DIM * ZX) + x;
    #pragma unroll 8
    for (int c4 = 0; c4 < E_DIM / 4; c4++) {
        float4 v = er[c4];
        ob[(size_t)(c4 * 4 + 0) * ZX] = v.x;
        ob[(size_t)(c4 * 4 + 1) * ZX] = v.y;
        ob[(size_t)(c4 * 4 + 2) * ZX] = v.z;
        ob[(size_t)(c4 * 4 + 3) * ZX] = v.w;
    }
}

// ---------------- n = sum(new_cluster), usage ----------------
__global__ void k_stats(const float* __restrict__ cluster_size, const int* __restrict__ cnt,
                        float* __restrict__ nval, float* __restrict__ out_usage) {
    __shared__ float sn[256];
    __shared__ float sc[256];
    int tid = threadIdx.x;
    float ns = 0.f, c = 0.f;
    for (int j = tid; j < N_E; j += 256) {
        float nt = (float)cnt[j];
        ns += cluster_size[j] * DECAY + (1.f - DECAY) * nt;
        c += (nt > 0.f) ? 1.f : 0.f;
    }
    sn[tid] = ns; sc[tid] = c;
    __syncthreads();
    for (int off = 128; off; off >>= 1) {
        if (tid < off) { sn[tid] += sn[tid + off]; sc[tid] += sc[tid + off]; }
        __syncthreads();
    }
    if (tid == 0) { *nval = sn[0]; *out_usage = sc[0] / (float)N_E; }
}

// ---------------- EMA epilogue ----------------
__global__ void k_final(const float* __restrict__ cluster_size, const int* __restrict__ cnt,
                        const float* __restrict__ emb_avg, const float* __restrict__ dw,
                        const float* __restrict__ nval,
                        float* __restrict__ out_cluster, float* __restrict__ out_avg,
                        float* __restrict__ out_embed) {
    int j = blockIdx.x;
    int k = threadIdx.x;
    float nc = cluster_size[j] * DECAY + (1.f - DECAY) * (float)cnt[j];
    float n = *nval;
    float cs = (nc + EPSV) / (n + (float)N_E * EPSV) * n;
    float na = emb_avg[(size_t)j * E_DIM + k] * DECAY + (1.f - DECAY) * dw[(size_t)j * E_DIM + k];
    out_avg[(size_t)j * E_DIM + k] = na;
    out_embed[(size_t)j * E_DIM + k] = na / cs;
    if (k == 0) out_cluster[j] = nc;
}

extern "C" void kernel_launch(void* const* d_in, const int* in_sizes, int n_in,
                              void* d_out, int out_size, void* d_ws, size_t ws_size,
                              hipStream_t stream) {
    const float* z            = (const float*)d_in[0];
    const float* emb          = (const float*)d_in[1];
    const float* cluster_size = (const float*)d_in[2];
    const float* emb_avg      = (const float*)d_in[3];
    float* out = (float*)d_out;

    // ---- d_ws layout (bytes), total ~34 MB ----
    char* ws = (char*)d_ws;
    unsigned short* zh   = (unsigned short*)(ws + 0);          // 16,777,216
    unsigned short* zl   = (unsigned short*)(ws + 16777216);   // 16,777,216
    float* enorm32       = (float*)(ws + 33554432);            // 16,384
    double* enorm64      = (double*)(ws + 33570816);           // 32,768
    int* idx32           = (int*)(ws + 33603584);              // 131,072
    int* flagList        = (int*)(ws + 33734656);              // 131,072
    int* cnt             = (int*)(ws + 33865728);              // 16,384
    int* offs            = (int*)(ws + 33882112);              // 16,384
    int* flagCnt         = (int*)(ws + 33898496);              // 64
    float* nval          = (float*)(ws + 33898560);            // 64

    // ---- scratch inside d_out's zq region (written last by k_zq) ----
    float* pm1           = out + 0;                 // 1,048,576 f
    float* pm2           = out + 1048576;           // 1,048,576 f
    int*   pidx          = (int*)(out + 2097152);   // 1,048,576 i
    float* dw            = out + 3145728;           // 1,048,576 f
    unsigned short* Bp   = (unsigned short*)(out + 4194304);   // 6,291,456 B
    int*   tokList       = (int*)(out + 5767168);   // 32,768 i

    // ---- output sections ----
    float* out_zq      = out + 0;
    float* out_idx     = out + 8388608;
    float* out_cluster = out + 8421376;
    float* out_avg     = out + 8425472;
    float* out_embed   = out + 9474048;
    float* out_usage   = out + 10522624;

    hipLaunchKernelGGL(k_prep_z, dim3(2048), dim3(256), 0, stream, z, zh, zl);
    hipLaunchKernelGGL(k_prep_e, dim3(1024), dim3(256), 0, stream, emb, Bp, enorm32, enorm64);
    hipLaunchKernelGGL(k_init,   dim3(16),   dim3(256), 0, stream, cnt, flagCnt);
    hipLaunchKernelGGL(k_dist,   dim3(256, NJB), dim3(256), 0, stream,
                       zh, zl, Bp, enorm32, pm1, pm2, pidx);
    hipLaunchKernelGGL(k_merge,  dim3(128), dim3(256), 0, stream,
                       pm1, pm2, pidx, idx32, flagList, flagCnt);
    hipLaunchKernelGGL(k_recheck, dim3(256), dim3(256), 0, stream,
                       z, emb, enorm64, flagList, flagCnt, idx32);
    hipLaunchKernelGGL(k_count,  dim3(128), dim3(256), 0, stream, idx32, cnt, out_idx);
    hipLaunchKernelGGL(k_scan,   dim3(1), dim3(1024), 0, stream, cnt, offs);
    hipLaunchKernelGGL(k_place,  dim3(128), dim3(256), 0, stream, idx32, offs, tokList);
    hipLaunchKernelGGL(k_dw,     dim3(4096), dim3(64), 0, stream, zh, zl, cnt, offs, tokList, dw);
    hipLaunchKernelGGL(k_stats,  dim3(1), dim3(256), 0, stream, cluster_size, cnt, nval, out_usage);
    hipLaunchKernelGGL(k_final,  dim3(4096), dim3(256), 0, stream,
                       cluster_size, cnt, emb_avg, dw, nval,
                       out_cluster, out_avg, out_embed);
    hipLaunchKernelGGL(k_zq,     dim3(128), dim3(256), 0, stream, emb, idx32, out_zq);
}

// Round 3
// 625.924 us; speedup vs baseline: 4.0978x; 1.4284x over previous
//
#include <hip/hip_runtime.h>

#define N_E   4096
#define E_DIM 256
#define NTOK  32768
#define ZX    4096
#define DECAY 0.99f
#define EPSV  1e-5f
#define TAU   0.05f
#define NJB   32        // N_E / 128 j-blocks
#define KP    768       // split-GEMM K

typedef __attribute__((ext_vector_type(8))) short short8;
typedef __attribute__((ext_vector_type(4))) float f32x4;

__device__ __forceinline__ unsigned short f2bf(float x) {
    unsigned u = __float_as_uint(x);
    unsigned r = (u + 0x7fff + ((u >> 16) & 1)) >> 16;
    return (unsigned short)r;
}
__device__ __forceinline__ float bf2f(unsigned short h) {
    return __uint_as_float(((unsigned)h) << 16);
}
__device__ __forceinline__ void gload16(const void* g, void* l) {
    __builtin_amdgcn_global_load_lds(
        (const __attribute__((address_space(1))) char*)g,
        (__attribute__((address_space(3))) char*)l, 16, 0, 0);
}

// ---------------- prep z: (b,c,x) fp32 -> zh/zl [t][c] bf16 ----------------
__global__ void k_prep_z(const float* __restrict__ z,
                         unsigned short* __restrict__ zh, unsigned short* __restrict__ zl) {
    __shared__ float lt[64][65];
    const int bid = blockIdx.x;
    const int xt = bid & 63, ct = (bid >> 6) & 3, b = bid >> 8;
    const int tid = threadIdx.x;
    #pragma unroll
    for (int r = 0; r < 4; ++r) {
        int cy = r * 16 + (tid >> 4);
        int xx4 = tid & 15;
        float4 v = ((const float4*)z)[(size_t)(b * 256 + ct * 64 + cy) * 1024 + xt * 16 + xx4];
        lt[cy][xx4 * 4 + 0] = v.x; lt[cy][xx4 * 4 + 1] = v.y;
        lt[cy][xx4 * 4 + 2] = v.z; lt[cy][xx4 * 4 + 3] = v.w;
    }
    __syncthreads();
    #pragma unroll
    for (int it = 0; it < 2; ++it) {
        int tl = it * 32 + (tid >> 3);
        int c8 = tid & 7;
        unsigned short h[8], l[8];
        #pragma unroll
        for (int u = 0; u < 8; ++u) {
            float f = lt[c8 * 8 + u][tl];
            h[u] = f2bf(f);
            l[u] = f2bf(f - bf2f(h[u]));
        }
        size_t t = (size_t)(b * 4096 + xt * 64 + tl);
        size_t o = t * 256 + ct * 64 + c8 * 8;
        *(ushort4*)&zh[o]     = make_ushort4(h[0], h[1], h[2], h[3]);
        *(ushort4*)&zh[o + 4] = make_ushort4(h[4], h[5], h[6], h[7]);
        *(ushort4*)&zl[o]     = make_ushort4(l[0], l[1], l[2], l[3]);
        *(ushort4*)&zl[o + 4] = make_ushort4(l[4], l[5], l[6], l[7]);
    }
}

// ---------------- prep emb: B' = [e_hi | e_lo | e_hi], enorm32/64 ----------------
__global__ void k_prep_e(const float* __restrict__ emb, unsigned short* __restrict__ Bp,
                         float* __restrict__ enorm32, double* __restrict__ enorm64) {
    int j = blockIdx.x * 4 + (threadIdx.x >> 6);
    int lane = threadIdx.x & 63;
    float4 v = ((const float4*)emb)[(size_t)j * 64 + lane];
    float f[4] = {v.x, v.y, v.z, v.w};
    unsigned short h[4], l[4];
    #pragma unroll
    for (int u = 0; u < 4; ++u) {
        h[u] = f2bf(f[u]);
        l[u] = f2bf(f[u] - bf2f(h[u]));
    }
    size_t base = (size_t)j * KP;
    *(ushort4*)&Bp[base + lane * 4]       = make_ushort4(h[0], h[1], h[2], h[3]);
    *(ushort4*)&Bp[base + 256 + lane * 4] = make_ushort4(l[0], l[1], l[2], l[3]);
    *(ushort4*)&Bp[base + 512 + lane * 4] = make_ushort4(h[0], h[1], h[2], h[3]);
    double s = 0.0;
    #pragma unroll
    for (int u = 0; u < 4; ++u) s += (double)f[u] * (double)f[u];
    #pragma unroll
    for (int off = 32; off; off >>= 1) s += __shfl_down(s, off, 64);
    if (lane == 0) { enorm32[j] = (float)s; enorm64[j] = s; }
}

// ---------------- init ----------------
__global__ void k_init(int* __restrict__ cnt, int* __restrict__ flagCount) {
    int gid = blockIdx.x * blockDim.x + threadIdx.x;
    if (gid < N_E) cnt[gid] = 0;
    if (gid == 0) *flagCount = 0;
}

// ---------------- MFMA distance / top-2 argmin (dbuf + T2 swizzle) ----------------
__global__ __launch_bounds__(256) void k_dist(
        const unsigned short* __restrict__ zh, const unsigned short* __restrict__ zl,
        const unsigned short* __restrict__ Bp, const float* __restrict__ enorm32,
        float* __restrict__ pm1, float* __restrict__ pm2, int* __restrict__ pidx) {
    __shared__ __align__(16) char smem[65536];   // 2 x (16KB A + 16KB B)
    const int tid = threadIdx.x;
    const int lane = tid & 63;
    const int w = tid >> 6;
    const int wr = w >> 1, wc = w & 1;
    const int t0 = blockIdx.x * 128;
    const int jb = blockIdx.y;
    const int j0 = jb * 128;
    // pre-swizzled source byte offset within a 128B K-chunk row (rule #21):
    // LDS[r][c] will hold data[r][c ^ ((r&7)<<4)]; r&7 == lane>>3 at write time.
    const int sw16 = (((lane & 7) ^ (lane >> 3)) << 4);
    const int rowsub = lane >> 3;     // row within 8-row seg

    f32x4 acc[4][4];
    #pragma unroll
    for (int m = 0; m < 4; ++m)
        #pragma unroll
        for (int n = 0; n < 4; ++n)
            acc[m][n] = (f32x4){0.f, 0.f, 0.f, 0.f};

    auto stage = [&](int s, int buf) {
        const unsigned short* As = (s < 8) ? zh : zl;
        const int akb = (s & 3) * 128 + sw16;
        const int bkb = s * 128 + sw16;
        char* base = smem + buf * 32768;
        #pragma unroll
        for (int c = 0; c < 4; ++c) {
            int seg = w * 4 + c;
            int arow = t0 + seg * 8 + rowsub;
            int brow = j0 + seg * 8 + rowsub;
            gload16((const char*)As + (size_t)arow * 512 + akb, base + seg * 1024);
            gload16((const char*)Bp + (size_t)brow * 1536 + bkb, base + 16384 + seg * 1024);
        }
    };

    stage(0, 0);
    __syncthreads();
    for (int s = 0; s < 12; ++s) {
        const int buf = s & 1;
        if (s < 11) stage(s + 1, buf ^ 1);
        const int xr = ((lane & 7) << 4);   // read-side XOR (row&7 == lane&7 here)
        #pragma unroll
        for (int kk = 0; kk < 2; ++kk) {
            const int colb = (kk * 64 + ((lane >> 4) << 4)) ^ xr;
            short8 a[4], b[4];
            #pragma unroll
            for (int m = 0; m < 4; ++m)
                a[m] = *(const short8*)&smem[buf * 32768
                        + ((wr * 64 + m * 16 + (lane & 15)) << 7) + colb];
            #pragma unroll
            for (int n = 0; n < 4; ++n)
                b[n] = *(const short8*)&smem[buf * 32768 + 16384
                        + ((wc * 64 + n * 16 + (lane & 15)) << 7) + colb];
            #pragma unroll
            for (int m = 0; m < 4; ++m)
                #pragma unroll
                for (int n = 0; n < 4; ++n)
                    acc[m][n] = __builtin_amdgcn_mfma_f32_16x16x32_bf16(a[m], b[n], acc[m][n], 0, 0, 0);
        }
        __syncthreads();
    }

    // epilogue: score = ||e||^2 - 2 z.e ; per-token top-2 over this block's 128 codes
    float bm1[4][4], bm2[4][4]; int bx1[4][4];
    #pragma unroll
    for (int m = 0; m < 4; ++m)
        #pragma unroll
        for (int r = 0; r < 4; ++r) { bm1[m][r] = 3.4e38f; bm2[m][r] = 3.4e38f; bx1[m][r] = 0; }
    #pragma unroll
    for (int n = 0; n < 4; ++n) {
        int j = j0 + wc * 64 + n * 16 + (lane & 15);
        float en = enorm32[j];
        #pragma unroll
        for (int m = 0; m < 4; ++m)
            #pragma unroll
            for (int r = 0; r < 4; ++r) {
                float sc = fmaf(-2.f, acc[m][n][r], en);
                if (sc < bm1[m][r]) { bm2[m][r] = bm1[m][r]; bm1[m][r] = sc; bx1[m][r] = j; }
                else if (sc < bm2[m][r]) bm2[m][r] = sc;
            }
    }
    #pragma unroll
    for (int off = 8; off >= 1; off >>= 1) {
        #pragma unroll
        for (int m = 0; m < 4; ++m)
            #pragma unroll
            for (int r = 0; r < 4; ++r) {
                float om1 = __shfl_xor(bm1[m][r], off, 64);
                float om2 = __shfl_xor(bm2[m][r], off, 64);
                int   ox1 = __shfl_xor(bx1[m][r], off, 64);
                bool take = (om1 < bm1[m][r]) || (om1 == bm1[m][r] && ox1 < bx1[m][r]);
                float n2 = take ? fminf(bm1[m][r], om2) : fminf(om1, bm2[m][r]);
                if (take) { bm1[m][r] = om1; bx1[m][r] = ox1; }
                bm2[m][r] = n2;
            }
    }
    // merge the two wc-waves via LDS (tiles dead after final barrier)
    float* mb1 = (float*)smem;            // [2][128]
    float* mb2 = (float*)(smem + 1024);
    int*   mbi = (int*)(smem + 2048);
    if ((lane & 15) == 0) {
        int g = lane >> 4;
        #pragma unroll
        for (int m = 0; m < 4; ++m)
            #pragma unroll
            for (int r = 0; r < 4; ++r) {
                int tl = wr * 64 + m * 16 + g * 4 + r;
                mb1[wc * 128 + tl] = bm1[m][r];
                mb2[wc * 128 + tl] = bm2[m][r];
                mbi[wc * 128 + tl] = bx1[m][r];
            }
    }
    __syncthreads();
    if (tid < 128) {
        float a1 = mb1[tid], a2 = mb2[tid]; int ai = mbi[tid];
        float c1 = mb1[128 + tid], c2 = mb2[128 + tid]; int ci = mbi[128 + tid];
        bool take = (c1 < a1) || (c1 == a1 && ci < ai);
        float m1 = take ? c1 : a1;
        int   x1 = take ? ci : ai;
        float m2 = take ? fminf(a1, c2) : fminf(c1, a2);
        int t = t0 + tid;
        pm1[(size_t)jb * NTOK + t] = m1;
        pm2[(size_t)jb * NTOK + t] = m2;
        pidx[(size_t)jb * NTOK + t] = x1;
    }
}

// ---------------- merge j-blocks, histogram, idx out, flag near-ties ----------------
__global__ void k_merge(const float* __restrict__ pm1, const float* __restrict__ pm2,
                        const int* __restrict__ pidx, int* __restrict__ idx32,
                        int* __restrict__ cnt, float* __restrict__ out_idx,
                        int* __restrict__ flagList, int* __restrict__ flagCount) {
    int t = blockIdx.x * blockDim.x + threadIdx.x;
    if (t >= NTOK) return;
    float m1 = 3.4e38f, m2 = 3.4e38f; int x1 = 0x7fffffff;
    for (int s = 0; s < NJB; s++) {
        float om1 = pm1[(size_t)s * NTOK + t], om2 = pm2[(size_t)s * NTOK + t];
        int ox1 = pidx[(size_t)s * NTOK + t];
        bool take = (om1 < m1) || (om1 == m1 && ox1 < x1);
        float n2 = take ? fminf(m1, om2) : fminf(om1, m2);
        if (take) { m1 = om1; x1 = ox1; }
        m2 = n2;
    }
    idx32[t] = x1;
    atomicAdd(&cnt[x1], 1);
    out_idx[t] = (float)x1;
    if (m2 - m1 < TAU) {
        int p = atomicAdd(flagCount, 1);
        flagList[p] = t;
    }
}

// ---------------- fp64 recheck of flagged tokens (patches idx/cnt/out_idx) ----------------
__global__ void k_recheck(const float* __restrict__ z, const float* __restrict__ emb,
                          const double* __restrict__ enorm64,
                          const int* __restrict__ flagList, const int* __restrict__ flagCount,
                          int* __restrict__ idx32, int* __restrict__ cnt,
                          float* __restrict__ out_idx) {
    __shared__ float zrow[E_DIM];
    __shared__ double rv[1024];
    __shared__ int ri[1024];
    const int tid = threadIdx.x;
    const int nf = *flagCount;
    for (int f = blockIdx.x; f < nf; f += gridDim.x) {
        const int t = flagList[f];
        const int b = t >> 12, x = t & 4095;
        __syncthreads();
        if (tid < E_DIM) zrow[tid] = z[(size_t)(b * 256 + tid) * 4096 + x];
        __syncthreads();
        double best = 1e300; int bi = 0x7fffffff;
        for (int s = 0; s < N_E / 1024; s++) {
            int j = s * 1024 + tid;
            const float* er = emb + (size_t)j * E_DIM;
            double a1 = 0.0;
            for (int k = 0; k < E_DIM; k++)
                a1 = fma((double)er[k], (double)zrow[k], a1);
            double d = enorm64[j] - 2.0 * a1;
            if (d < best || (d == best && j < bi)) { best = d; bi = j; }
        }
        rv[tid] = best; ri[tid] = bi;
        __syncthreads();
        for (int off = 512; off; off >>= 1) {
            if (tid < off) {
                if (rv[tid + off] < rv[tid] ||
                    (rv[tid + off] == rv[tid] && ri[tid + off] < ri[tid])) {
                    rv[tid] = rv[tid + off]; ri[tid] = ri[tid + off];
                }
            }
            __syncthreads();
        }
        if (tid == 0) {
            int old = idx32[t];
            int nw = ri[0];
            if (nw != old) {
                idx32[t] = nw;
                out_idx[t] = (float)nw;
                atomicSub(&cnt[old], 1);
                atomicAdd(&cnt[nw], 1);
            }
        }
        __syncthreads();
    }
}

// ---------------- exclusive scan of cnt[4096] ----------------
__global__ void k_scan(const int* __restrict__ cnt, int* __restrict__ offs) {
    __shared__ int sc[1024];
    int tid = threadIdx.x;
    int c0 = cnt[tid * 4], c1 = cnt[tid * 4 + 1], c2 = cnt[tid * 4 + 2], c3 = cnt[tid * 4 + 3];
    int ls = c0 + c1 + c2 + c3;
    sc[tid] = ls;
    __syncthreads();
    for (int off = 1; off < 1024; off <<= 1) {
        int v = (tid >= off) ? sc[tid - off] : 0;
        __syncthreads();
        sc[tid] += v;
        __syncthreads();
    }
    int base = sc[tid] - ls;
    offs[tid * 4] = base;
    offs[tid * 4 + 1] = base + c0;
    offs[tid * 4 + 2] = base + c0 + c1;
    offs[tid * 4 + 3] = base + c0 + c1 + c2;
}

// ---------------- place tokens into per-code lists ----------------
__global__ void k_place(const int* __restrict__ idx32, int* __restrict__ offs,
                        int* __restrict__ tokList) {
    int t = blockIdx.x * blockDim.x + threadIdx.x;
    if (t >= NTOK) return;
    int j = idx32[t];
    int p = atomicAdd(&offs[j], 1);
    tokList[p] = t;
}

// ---------------- dw: per-code coalesced reduction, 4 lane-groups ----------------
__global__ void k_dw(const unsigned short* __restrict__ zh, const unsigned short* __restrict__ zl,
                     const int* __restrict__ cnt, const int* __restrict__ offs,
                     const int* __restrict__ tokList, float* __restrict__ dw) {
    __shared__ float red[4][256];
    int j = blockIdx.x;
    int g = threadIdx.x >> 6;
    int lane = threadIdx.x & 63;
    int n = cnt[j];
    int s0 = offs[j] - n;     // offs holds end positions after k_place
    float4 acc = make_float4(0.f, 0.f, 0.f, 0.f);
    for (int i = g; i < n; i += 4) {
        int t = tokList[s0 + i];
        ushort4 h = *(const ushort4*)&zh[(size_t)t * 256 + lane * 4];
        ushort4 l = *(const ushort4*)&zl[(size_t)t * 256 + lane * 4];
        acc.x += bf2f(h.x) + bf2f(l.x);
        acc.y += bf2f(h.y) + bf2f(l.y);
        acc.z += bf2f(h.z) + bf2f(l.z);
        acc.w += bf2f(h.w) + bf2f(l.w);
    }
    red[g][lane * 4 + 0] = acc.x; red[g][lane * 4 + 1] = acc.y;
    red[g][lane * 4 + 2] = acc.z; red[g][lane * 4 + 3] = acc.w;
    __syncthreads();
    if (g == 0) {
        #pragma unroll
        for (int u = 0; u < 4; ++u) {
            int c = lane * 4 + u;
            dw[(size_t)j * 256 + c] = red[0][c] + red[1][c] + red[2][c] + red[3][c];
        }
    }
}

// ---------------- zq gather ----------------
__global__ void k_zq(const float* __restrict__ emb, const int* __restrict__ idx32,
                     float* __restrict__ out_zq) {
    int t = blockIdx.x * blockDim.x + threadIdx.x;
    int j = idx32[t];
    int b = t >> 12, x = t & 4095;
    const float4* er = (const float4*)(emb + (size_t)j * E_DIM);
    float* ob = out_zq + (size_t)b * (E_DIM * ZX) + x;
    #pragma unroll 8
    for (int c4 = 0; c4 < E_DIM / 4; c4++) {
        float4 v = er[c4];
        ob[(size_t)(c4 * 4 + 0) * ZX] = v.x;
        ob[(size_t)(c4 * 4 + 1) * ZX] = v.y;
        ob[(size_t)(c4 * 4 + 2) * ZX] = v.z;
        ob[(size_t)(c4 * 4 + 3) * ZX] = v.w;
    }
}

// ---------------- n = sum(new_cluster), usage ----------------
__global__ void k_stats(const float* __restrict__ cluster_size, const int* __restrict__ cnt,
                        float* __restrict__ nval, float* __restrict__ out_usage) {
    __shared__ float sn[256];
    __shared__ float sc[256];
    int tid = threadIdx.x;
    float ns = 0.f, c = 0.f;
    for (int j = tid; j < N_E; j += 256) {
        float nt = (float)cnt[j];
        ns += cluster_size[j] * DECAY + (1.f - DECAY) * nt;
        c += (nt > 0.f) ? 1.f : 0.f;
    }
    sn[tid] = ns; sc[tid] = c;
    __syncthreads();
    for (int off = 128; off; off >>= 1) {
        if (tid < off) { sn[tid] += sn[tid + off]; sc[tid] += sc[tid + off]; }
        __syncthreads();
    }
    if (tid == 0) { *nval = sn[0]; *out_usage = sc[0] / (float)N_E; }
}

// ---------------- EMA epilogue ----------------
__global__ void k_final(const float* __restrict__ cluster_size, const int* __restrict__ cnt,
                        const float* __restrict__ emb_avg, const float* __restrict__ dw,
                        const float* __restrict__ nval,
                        float* __restrict__ out_cluster, float* __restrict__ out_avg,
                        float* __restrict__ out_embed) {
    int j = blockIdx.x;
    int k = threadIdx.x;
    float nc = cluster_size[j] * DECAY + (1.f - DECAY) * (float)cnt[j];
    float n = *nval;
    float cs = (nc + EPSV) / (n + (float)N_E * EPSV) * n;
    float na = emb_avg[(size_t)j * E_DIM + k] * DECAY + (1.f - DECAY) * dw[(size_t)j * E_DIM + k];
    out_avg[(size_t)j * E_DIM + k] = na;
    out_embed[(size_t)j * E_DIM + k] = na / cs;
    if (k == 0) out_cluster[j] = nc;
}

extern "C" void kernel_launch(void* const* d_in, const int* in_sizes, int n_in,
                              void* d_out, int out_size, void* d_ws, size_t ws_size,
                              hipStream_t stream) {
    const float* z            = (const float*)d_in[0];
    const float* emb          = (const float*)d_in[1];
    const float* cluster_size = (const float*)d_in[2];
    const float* emb_avg      = (const float*)d_in[3];
    float* out = (float*)d_out;

    // ---- d_ws layout (bytes), total ~34 MB ----
    char* ws = (char*)d_ws;
    unsigned short* zh   = (unsigned short*)(ws + 0);          // 16,777,216
    unsigned short* zl   = (unsigned short*)(ws + 16777216);   // 16,777,216
    float* enorm32       = (float*)(ws + 33554432);            // 16,384
    double* enorm64      = (double*)(ws + 33570816);           // 32,768
    int* idx32           = (int*)(ws + 33603584);              // 131,072
    int* flagList        = (int*)(ws + 33734656);              // 131,072
    int* cnt             = (int*)(ws + 33865728);              // 16,384
    int* offs            = (int*)(ws + 33882112);              // 16,384
    int* flagCnt         = (int*)(ws + 33898496);              // 64
    float* nval          = (float*)(ws + 33898560);            // 64

    // ---- scratch inside d_out's zq region (written last by k_zq) ----
    float* pm1           = out + 0;                 // 1,048,576 f
    float* pm2           = out + 1048576;           // 1,048,576 f
    int*   pidx          = (int*)(out + 2097152);   // 1,048,576 i
    float* dw            = out + 3145728;           // 1,048,576 f
    unsigned short* Bp   = (unsigned short*)(out + 4194304);   // 6,291,456 B
    int*   tokList       = (int*)(out + 5767168);   // 32,768 i

    // ---- output sections ----
    float* out_zq      = out + 0;
    float* out_idx     = out + 8388608;
    float* out_cluster = out + 8421376;
    float* out_avg     = out + 8425472;
    float* out_embed   = out + 9474048;
    float* out_usage   = out + 10522624;

    hipLaunchKernelGGL(k_prep_z, dim3(2048), dim3(256), 0, stream, z, zh, zl);
    hipLaunchKernelGGL(k_prep_e, dim3(1024), dim3(256), 0, stream, emb, Bp, enorm32, enorm64);
    hipLaunchKernelGGL(k_init,   dim3(16),   dim3(256), 0, stream, cnt, flagCnt);
    hipLaunchKernelGGL(k_dist,   dim3(256, NJB), dim3(256), 0, stream,
                       zh, zl, Bp, enorm32, pm1, pm2, pidx);
    hipLaunchKernelGGL(k_merge,  dim3(128), dim3(256), 0, stream,
                       pm1, pm2, pidx, idx32, cnt, out_idx, flagList, flagCnt);
    hipLaunchKernelGGL(k_recheck, dim3(512), dim3(1024), 0, stream,
                       z, emb, enorm64, flagList, flagCnt, idx32, cnt, out_idx);
    hipLaunchKernelGGL(k_scan,   dim3(1), dim3(1024), 0, stream, cnt, offs);
    hipLaunchKernelGGL(k_place,  dim3(128), dim3(256), 0, stream, idx32, offs, tokList);
    hipLaunchKernelGGL(k_dw,     dim3(4096), dim3(256), 0, stream, zh, zl, cnt, offs, tokList, dw);
    hipLaunchKernelGGL(k_stats,  dim3(1), dim3(256), 0, stream, cluster_size, cnt, nval, out_usage);
    hipLaunchKernelGGL(k_final,  dim3(4096), dim3(256), 0, stream,
                       cluster_size, cnt, emb_avg, dw, nval,
                       out_cluster, out_avg, out_embed);
    hipLaunchKernelGGL(k_zq,     dim3(128), dim3(256), 0, stream, emb, idx32, out_zq);
}